// Round 1
// baseline (310.276 us; speedup 1.0000x reference)
//
#include <hip/hip_runtime.h>
#include <stdint.h>

#define BB 4
#define SDIM 128
#define S2 (SDIM*SDIM)          // 16384
#define S3 ((size_t)SDIM*S2)    // 2097152

// Per-wave probe: detect bool storage width (1B vs 4B) from structure
// (valid is a prefix of >=64 trues; element S-1 is always false), then
// return len[b] = popcount of the valid prefix. All 64 lanes participate.
__device__ __forceinline__ int probe_len(const void* em, int b, int lane) {
    const unsigned char* p8 = (const unsigned char*)em;
    const int* p32 = (const int*)em;
    const int t0 = lane, t1 = lane + 64;
    const size_t i0 = (size_t)b*S2 + (size_t)t0*SDIM + t0;
    const size_t i1 = (size_t)b*S2 + (size_t)t1*SDIM + t1;
    const unsigned char a0 = p8[i0], a1 = p8[i1];
    const bool ok = (a0 != 0) && (t1 != SDIM-1 || a1 == 0);
    const unsigned long long mok = __ballot(ok);
    const bool use8 = (mok == ~0ull);   // wave-uniform
    int v0, v1;
    if (use8) { v0 = (a0 != 0); v1 = (a1 != 0); }
    else      { v0 = (p32[i0] != 0); v1 = (p32[i1] != 0); }
    return __popcll(__ballot(v0)) + __popcll(__ballot(v1));
}

__device__ __forceinline__ float sigf(float x) { return 1.f / (1.f + expf(-x)); }

// Fused: q_edge/q_span init + pe/peT/ps init (BOTH ping-pong buffers; positions
// never touched by k_upd keep constant q, so their sigmoid is constant across
// iterations) + splitsum precompute. Block = (b, i).
__global__ __launch_bounds__(256) void k_prep(
    const float* __restrict__ s_edge, const float* __restrict__ s_const,
    const float* __restrict__ s_split, const void* __restrict__ em,
    float* __restrict__ q_edge, float* __restrict__ q_span,
    float* __restrict__ splitsum,
    float* __restrict__ peA, float* __restrict__ peB,
    float* __restrict__ peTA, float* __restrict__ peTB,
    float* __restrict__ psA, float* __restrict__ psB) {
    const int b = blockIdx.x >> 7, i = blockIdx.x & 127;
    const int tid = threadIdx.x, lane = tid & 63;
    const int len = probe_len(em, b, lane);
    const size_t vb = (size_t)b*S2;
    if (tid < SDIM) {
        const size_t ro = vb + (size_t)i*SDIM + tid;
        const float qe = s_edge[ro];
        const float qs = (i <= tid) ? s_const[ro] : s_const[vb + (size_t)tid*SDIM + i];
        q_edge[ro] = qe;
        q_span[ro] = qs;
        const float se = sigf(qe), ss = sigf(qs);
        peA[ro] = se; peB[ro] = se;
        psA[ro] = ss; psB[ro] = ss;
        const size_t to = vb + (size_t)tid*SDIM + i;
        peTA[to] = se; peTB[to] = se;
    }
    const int g = tid >> 5;            // j-group 0..7
    const int kq = (tid & 31) * 4;     // k base
    float4 acc = make_float4(0.f, 0.f, 0.f, 0.f);
    if (i >= 1 && i < len && kq < len) {
        const float* base = s_split + (size_t)b*S3 + (size_t)i*S2;
        int j = i + g;
        for (; j + 24 < len; j += 32) {   // 4 loads in flight
            float4 v0 = *(const float4*)(base + (size_t)(j     )*SDIM + kq);
            float4 v1 = *(const float4*)(base + (size_t)(j +  8)*SDIM + kq);
            float4 v2 = *(const float4*)(base + (size_t)(j + 16)*SDIM + kq);
            float4 v3 = *(const float4*)(base + (size_t)(j + 24)*SDIM + kq);
            acc.x += ((j    != kq+0) ? v0.x : 0.f) + ((j+8  != kq+0) ? v1.x : 0.f)
                   + ((j+16 != kq+0) ? v2.x : 0.f) + ((j+24 != kq+0) ? v3.x : 0.f);
            acc.y += ((j    != kq+1) ? v0.y : 0.f) + ((j+8  != kq+1) ? v1.y : 0.f)
                   + ((j+16 != kq+1) ? v2.y : 0.f) + ((j+24 != kq+1) ? v3.y : 0.f);
            acc.z += ((j    != kq+2) ? v0.z : 0.f) + ((j+8  != kq+2) ? v1.z : 0.f)
                   + ((j+16 != kq+2) ? v2.z : 0.f) + ((j+24 != kq+2) ? v3.z : 0.f);
            acc.w += ((j    != kq+3) ? v0.w : 0.f) + ((j+8  != kq+3) ? v1.w : 0.f)
                   + ((j+16 != kq+3) ? v2.w : 0.f) + ((j+24 != kq+3) ? v3.w : 0.f);
        }
        for (; j < len; j += 8) {
            float4 v0 = *(const float4*)(base + (size_t)j*SDIM + kq);
            acc.x += (j != kq+0) ? v0.x : 0.f;
            acc.y += (j != kq+1) ? v0.y : 0.f;
            acc.z += (j != kq+2) ? v0.z : 0.f;
            acc.w += (j != kq+3) ? v0.w : 0.f;
        }
    }
    __shared__ float red[8][SDIM];
    *(float4*)&red[g][kq] = acc;
    __syncthreads();
    if (tid < SDIM) {
        float s = 0.f;
        #pragma unroll
        for (int gg = 0; gg < 8; ++gg) s += red[gg][tid];
        splitsum[vb + (size_t)i*SDIM + tid] = (tid >= 1 && tid < len) ? s : 0.f;
    }
}

// Fused per-iteration update, v2: one block owns one whole output row.
//   gid&1==0 : edge row h = gid>>3, batch b = (gid>>1)&3  (all 128 m)
//   gid&1==1 : span row i likewise (all 128 j)
// Depth-4 software pipeline with NAMED double-buffer registers (no runtime
// indexing -> stays in VGPRs, compiler keeps ~24 loads in flight per wave).
// 1024 blocks x 4 waves = 4096 waves == exactly full-device residency at
// 4 waves/SIMD -> no dispatch churn.
// Epilogue writes the NEXT iteration's sigmoid into the ping-pong buffers
// (each q element has a unique writer block, so this is race-free).
__global__ __launch_bounds__(256) void k_upd(
    const float* __restrict__ s_sib, const float* __restrict__ s_cop,
    const float* __restrict__ s_grd, const float* __restrict__ s_ep,
    const float* __restrict__ s_hb,  const float* __restrict__ s_he,
    const float* __restrict__ peA, const float* __restrict__ peTA,
    const float* __restrict__ psA, const float* __restrict__ splitsum,
    const void* __restrict__ em,
    float* __restrict__ q_edge, float* __restrict__ q_span,
    float* __restrict__ peB, float* __restrict__ peTB, float* __restrict__ psB) {
    const int gid  = blockIdx.x;
    const int part = gid & 1, b = (gid >> 1) & 3, row = gid >> 3;
    const int tid = threadIdx.x, wave = tid >> 6, lane = tid & 63;
    const int half = lane >> 5, sq = (lane & 31) * 4;
    const int len = probe_len(em, b, lane);
    const int lm1 = len - 1;
    const int sqa = min(sq, lm1 & ~3);     // clamped column base (address only)
    const size_t vb = (size_t)b*S2;
    const int nst = (len + 7) >> 3;        // 8..16 row-steps of 8
    const int nit = (nst + 3) & ~3;        // rotation-friendly (8/12/16)

    if (part == 0) {
        const int h = row;
        if (h >= len) return;
        const size_t tb = (size_t)b*S3 + (size_t)h*S2;
        const size_t hrow = vb + (size_t)h*SDIM;
        const float4 pe4 = *(const float4*)(peA + hrow + sqa);

        float4 sib0,cop0,grd0,epv0,pet0,psv0; float qo0;
        float4 sib1,cop1,grd1,epv1,pet1,psv1; float qo1;
        float4 sib2,cop2,grd2,epv2,pet2,psv2; float qo2;
        float4 sib3,cop3,grd3,epv3,pet3,psv3; float qo3;

#define ELOAD(B, T) { \
        const int tt = min((T), nst-1); \
        const int mc_ = min(tt*8 + 2*wave + half, lm1); \
        const size_t ro = tb + (size_t)mc_*SDIM + sqa; \
        sib##B = *(const float4*)(s_sib + ro); \
        cop##B = *(const float4*)(s_cop + ro); \
        grd##B = *(const float4*)(s_grd + ro); \
        epv##B = *(const float4*)(s_ep  + ro); \
        const size_t vo = vb + (size_t)mc_*SDIM + sqa; \
        pet##B = *(const float4*)(peTA + vo); \
        psv##B = *(const float4*)(psA  + vo); \
        qo##B  = q_edge[hrow + mc_]; }

#define ETERM(B, C, F) { const int s = sq + C; \
        const bool bs = mv && (s < len) && (m != s); \
        const float fem = (bs && (h != s)) ? 1.f : 0.f; \
        const float fnc = (bs && ((m >= h && s >= h) || (m <= h && s <= h))) \
                          ? 1.f : 0.f; \
        r += fem * (sib##B.F*pe4.F + cop##B.F*pet##B.F + grd##B.F*psv##B.F) \
           + fnc * (epv##B.F*psv##B.F); }

#define ECOMP(B, T) { \
        const int m = (T)*8 + 2*wave + half; \
        const bool mv = (m < len); \
        float r = 0.f; \
        ETERM(B,0,x) ETERM(B,1,y) ETERM(B,2,z) ETERM(B,3,w) \
        r += __shfl_xor(r,16); r += __shfl_xor(r,8); r += __shfl_xor(r,4); \
        r += __shfl_xor(r,2);  r += __shfl_xor(r,1); \
        if ((lane & 31) == 0 && mv) { \
            const float qn = qo##B + r; \
            q_edge[hrow + m] = qn; \
            const float sg = sigf(qn); \
            peB[hrow + m] = sg; \
            peTB[vb + (size_t)m*SDIM + h] = sg; } }

        ELOAD(0,0) ELOAD(1,1) ELOAD(2,2) ELOAD(3,3)
        for (int t = 0; t < nit; t += 4) {
            const bool more = (t + 4 < nit);
            ECOMP(0,t)   if (more) ELOAD(0,t+4)
            ECOMP(1,t+1) if (more) ELOAD(1,t+5)
            ECOMP(2,t+2) if (more) ELOAD(2,t+6)
            ECOMP(3,t+3) if (more) ELOAD(3,t+7)
        }
#undef ELOAD
#undef ETERM
#undef ECOMP
    } else {
        const int i = row;
        if (i < 1 || i >= len) return;
        const size_t irow = vb + (size_t)i*SDIM;
        const float4 peTi4 = *(const float4*)(peTA + irow + sqa);

        float4 hb0,he0,ptj0; float qs0,pq0,ss0;
        float4 hb1,he1,ptj1; float qs1,pq1,ss1;
        float4 hb2,he2,ptj2; float qs2,pq2,ss2;
        float4 hb3,he3,ptj3; float qs3,pq3,ss3;

#define SLOAD(B, T) { \
        const int tt = min((T), nst-1); \
        const int jc_ = min(tt*8 + 2*wave + half, lm1); \
        hb##B  = *(const float4*)(s_hb + (size_t)b*S3 + (size_t)i*S2 + (size_t)jc_*SDIM + sqa); \
        he##B  = *(const float4*)(s_he + (size_t)b*S3 + (size_t)jc_*S2 + (size_t)i*SDIM + sqa); \
        ptj##B = *(const float4*)(peTA + vb + (size_t)jc_*SDIM + sqa); \
        qs##B  = q_span[irow + jc_]; \
        pq##B  = psA[irow + jc_]; \
        ss##B  = splitsum[irow + jc_]; }

#define STERM(B, C, F) { const int s = sq + C; \
        const float f = (act && s >= 1 && s < len && (s < i || s > j)) \
                        ? 1.f : 0.f; \
        r += f * (hb##B.F*peTi4.F + he##B.F*ptj##B.F); }

#define SCOMP(B, T) { \
        const int j = (T)*8 + 2*wave + half; \
        const bool act = (j > i) && (j < len); \
        float r = 0.f; \
        STERM(B,0,x) STERM(B,1,y) STERM(B,2,z) STERM(B,3,w) \
        r += __shfl_xor(r,16); r += __shfl_xor(r,8); r += __shfl_xor(r,4); \
        r += __shfl_xor(r,2);  r += __shfl_xor(r,1); \
        if ((lane & 31) == 0 && j >= 1 && j < len) { \
            const float qn = qs##B + r + pq##B * ss##B; \
            q_span[irow + j] = qn; \
            psB[irow + j] = sigf(qn); } }

        SLOAD(0,0) SLOAD(1,1) SLOAD(2,2) SLOAD(3,3)
        for (int t = 0; t < nit; t += 4) {
            const bool more = (t + 4 < nit);
            SCOMP(0,t)   if (more) SLOAD(0,t+4)
            SCOMP(1,t+1) if (more) SLOAD(1,t+5)
            SCOMP(2,t+2) if (more) SLOAD(2,t+6)
            SCOMP(3,t+3) if (more) SLOAD(3,t+7)
        }
#undef SLOAD
#undef STERM
#undef SCOMP
    }
}

extern "C" void kernel_launch(void* const* d_in, const int* in_sizes, int n_in,
                              void* d_out, int out_size, void* d_ws, size_t ws_size,
                              hipStream_t stream) {
    const float* s_edge  = (const float*)d_in[0];
    const float* s_const = (const float*)d_in[1];
    const float* s_sib   = (const float*)d_in[2];
    const float* s_cop   = (const float*)d_in[3];
    const float* s_grd   = (const float*)d_in[4];
    const float* s_ep    = (const float*)d_in[5];
    const float* s_split = (const float*)d_in[6];
    const float* s_hb    = (const float*)d_in[7];
    const float* s_he    = (const float*)d_in[8];
    const void*  em      = d_in[9];
    (void)in_sizes; (void)n_in; (void)out_size; (void)ws_size;

    float* q_edge = (float*)d_out;
    float* q_span = q_edge + (size_t)BB * S2;

    char* ws = (char*)d_ws;
    const size_t SZ = (size_t)BB * S2 * sizeof(float);   // 256 KiB
    float* splitsum = (float*)(ws);
    float* peA  = (float*)(ws + 1*SZ);
    float* peTA = (float*)(ws + 2*SZ);
    float* psA  = (float*)(ws + 3*SZ);
    float* peB  = (float*)(ws + 4*SZ);
    float* peTB = (float*)(ws + 5*SZ);
    float* psB  = (float*)(ws + 6*SZ);

    const int NB = BB * SDIM;  // 512
    hipLaunchKernelGGL(k_prep, dim3(NB), dim3(256), 0, stream,
                       s_edge, s_const, s_split, em, q_edge, q_span, splitsum,
                       peA, peB, peTA, peTB, psA, psB);
    for (int it = 0; it < 3; ++it) {
        const int s = it & 1;
        const float* peR  = s ? peB  : peA;
        const float* peTR = s ? peTB : peTA;
        const float* psR  = s ? psB  : psA;
        float* peW  = s ? peA  : peB;
        float* peTW = s ? peTA : peTB;
        float* psW  = s ? psA  : psB;
        hipLaunchKernelGGL(k_upd, dim3(2*NB), dim3(256), 0, stream,
                           s_sib, s_cop, s_grd, s_ep, s_hb, s_he,
                           peR, peTR, psR, splitsum, em,
                           q_edge, q_span, peW, peTW, psW);
    }
}

// Round 2
// 278.620 us; speedup vs baseline: 1.1136x; 1.1136x over previous
//
#include <hip/hip_runtime.h>
#include <stdint.h>

#define BB 4
#define SDIM 128
#define S2 (SDIM*SDIM)          // 16384
#define S3 ((size_t)SDIM*S2)    // 2097152

// Per-wave probe: detect bool storage width (1B vs 4B) from structure
// (valid is a prefix of >=64 trues; element S-1 is always false), then
// return len[b] = popcount of the valid prefix. All 64 lanes participate.
__device__ __forceinline__ int probe_len(const void* em, int b, int lane) {
    const unsigned char* p8 = (const unsigned char*)em;
    const int* p32 = (const int*)em;
    const int t0 = lane, t1 = lane + 64;
    const size_t i0 = (size_t)b*S2 + (size_t)t0*SDIM + t0;
    const size_t i1 = (size_t)b*S2 + (size_t)t1*SDIM + t1;
    const unsigned char a0 = p8[i0], a1 = p8[i1];
    const bool ok = (a0 != 0) && (t1 != SDIM-1 || a1 == 0);
    const unsigned long long mok = __ballot(ok);
    const bool use8 = (mok == ~0ull);   // wave-uniform
    int v0, v1;
    if (use8) { v0 = (a0 != 0); v1 = (a1 != 0); }
    else      { v0 = (p32[i0] != 0); v1 = (p32[i1] != 0); }
    return __popcll(__ballot(v0)) + __popcll(__ballot(v1));
}

__device__ __forceinline__ float sigf(float x) { return 1.f / (1.f + expf(-x)); }

// Fused: q init + pe/peT/ps init (both ping-pong buffers) + splitsum partials.
// Grid (B*S, 2). blockIdx.y splits the j-reduction: j - i = (g + 8y) + 16t.
// All 8 row-loads issued straight-line, sched_barrier, then reduce -> ONE
// memory-latency wait per block instead of ~4 serial bursts.
__global__ __launch_bounds__(256) void k_prep(
    const float* __restrict__ s_edge, const float* __restrict__ s_const,
    const float* __restrict__ s_split, const void* __restrict__ em,
    float* __restrict__ q_edge, float* __restrict__ q_span,
    float* __restrict__ split0, float* __restrict__ split1,
    float* __restrict__ peA, float* __restrict__ peB,
    float* __restrict__ peTA, float* __restrict__ peTB,
    float* __restrict__ psA, float* __restrict__ psB) {
    const int b = blockIdx.x >> 7, i = blockIdx.x & 127;
    const int y = blockIdx.y;
    const int tid = threadIdx.x, lane = tid & 63;
    const int len = probe_len(em, b, lane);
    const int lm1 = len - 1;
    const size_t vb = (size_t)b*S2;
    if (y == 0 && tid < SDIM) {
        const size_t ro = vb + (size_t)i*SDIM + tid;
        const float qe = s_edge[ro];
        const float qs = (i <= tid) ? s_const[ro] : s_const[vb + (size_t)tid*SDIM + i];
        q_edge[ro] = qe;
        q_span[ro] = qs;
        const float se = sigf(qe), ss = sigf(qs);
        peA[ro] = se; peB[ro] = se;
        psA[ro] = ss; psB[ro] = ss;
        const size_t to = vb + (size_t)tid*SDIM + i;
        peTA[to] = se; peTB[to] = se;
    }
    const int g = tid >> 5;            // j-group 0..7
    const int kq = (tid & 31) * 4;     // k base
    float4 acc = make_float4(0.f, 0.f, 0.f, 0.f);
    if (i >= 1 && i < len && kq < len) {
        const float* base = s_split + (size_t)b*S3 + (size_t)i*S2;
        const int j0 = i + g + 8*y;    // then stride 16; 8 steps cover j-i < 128
        float4 v[8]; int jv[8];
        #pragma unroll
        for (int t = 0; t < 8; ++t) {
            const int j = j0 + 16*t;
            jv[t] = j;
            const int jc = min(j, lm1);
            v[t] = *(const float4*)(base + (size_t)jc*SDIM + kq);
        }
        __builtin_amdgcn_sched_barrier(0);
        #pragma unroll
        for (int t = 0; t < 8; ++t) {
            const int j = jv[t];
            const bool jb = (j < len);
            acc.x += (jb && j != kq+0) ? v[t].x : 0.f;
            acc.y += (jb && j != kq+1) ? v[t].y : 0.f;
            acc.z += (jb && j != kq+2) ? v[t].z : 0.f;
            acc.w += (jb && j != kq+3) ? v[t].w : 0.f;
        }
    }
    __shared__ float red[8][SDIM];
    *(float4*)&red[g][kq] = acc;
    __syncthreads();
    if (tid < SDIM) {
        float s = 0.f;
        #pragma unroll
        for (int gg = 0; gg < 8; ++gg) s += red[gg][tid];
        float* out = y ? split1 : split0;
        out[vb + (size_t)i*SDIM + tid] = (tid >= 1 && tid < len) ? s : 0.f;
    }
}

// Fused per-iteration update, v3: round-0 geometry (4096 balanced blocks,
// blockIdx.y<4: edge m-chunk; else span j-chunk) + fused sigmoid epilogue
// (ping-pong pe/peT/ps; each q element has a unique writer block) + FORCED
// memory-level parallelism: all loads issued straight-line with clamped
// addresses, then __builtin_amdgcn_sched_barrier(0) pins them above the
// compute phase so ~25 loads stay in flight per wave (staggered vmcnt waits).
__global__ __launch_bounds__(256) void k_upd(
    const float* __restrict__ s_sib, const float* __restrict__ s_cop,
    const float* __restrict__ s_grd, const float* __restrict__ s_ep,
    const float* __restrict__ s_hb,  const float* __restrict__ s_he,
    const float* __restrict__ peA, const float* __restrict__ peTA,
    const float* __restrict__ psA,
    const float* __restrict__ split0, const float* __restrict__ split1,
    const void* __restrict__ em,
    float* __restrict__ q_edge, float* __restrict__ q_span,
    float* __restrict__ peB, float* __restrict__ peTB, float* __restrict__ psB) {
    const int b = blockIdx.x >> 7, row = blockIdx.x & 127;
    const int tid = threadIdx.x, wave = tid >> 6, lane = tid & 63;
    const int half = lane >> 5, sq = (lane & 31) * 4;
    const int len = probe_len(em, b, lane);
    const int lm1 = len - 1;
    const int sqa = min(sq, lm1 & ~3);     // clamped column base (address only)
    const size_t vb = (size_t)b*S2;

    if (blockIdx.y < 4) {
        const int h = row;
        if (h >= len) return;
        const int m0 = blockIdx.y * 32;
        if (m0 >= len) return;
        const size_t tb = (size_t)b*S3 + (size_t)h*S2;
        const size_t hrow = vb + (size_t)h*SDIM;
        const float4 pe4 = *(const float4*)(peA + hrow + sqa);
        int   mr[4];
        float4 sib[4], cop[4], grd[4], epv[4], pet[4], psv[4];
        float qo[4];
        #pragma unroll
        for (int it = 0; it < 4; ++it) {
            const int m = m0 + 8*it + 2*wave + half;
            mr[it] = m;
            const int mc = min(m, lm1);    // clamped row (address only)
            const size_t ro = tb + (size_t)mc*SDIM + sqa;
            sib[it] = *(const float4*)(s_sib + ro);
            cop[it] = *(const float4*)(s_cop + ro);
            grd[it] = *(const float4*)(s_grd + ro);
            epv[it] = *(const float4*)(s_ep  + ro);
            const size_t vo = vb + (size_t)mc*SDIM + sqa;
            pet[it] = *(const float4*)(peTA + vo);
            psv[it] = *(const float4*)(psA  + vo);
            qo[it]  = q_edge[hrow + mc];
        }
        __builtin_amdgcn_sched_barrier(0);
        #pragma unroll
        for (int it = 0; it < 4; ++it) {
            const int m = mr[it];
            const bool mv = (m < len);
            float r = 0.f;
            #define TERM(C, F) { const int s = sq + C;                               \
                const bool bs = mv && (s < len) && (m != s);                         \
                const float fem = (bs && (h != s)) ? 1.f : 0.f;                      \
                const float fnc = (bs && ((m >= h && s >= h) || (m <= h && s <= h))) \
                                  ? 1.f : 0.f;                                       \
                r += fem * (sib[it].F*pe4.F + cop[it].F*pet[it].F + grd[it].F*psv[it].F) \
                   + fnc * (epv[it].F*psv[it].F); }
            TERM(0, x) TERM(1, y) TERM(2, z) TERM(3, w)
            #undef TERM
            r += __shfl_xor(r, 16); r += __shfl_xor(r, 8); r += __shfl_xor(r, 4);
            r += __shfl_xor(r, 2);  r += __shfl_xor(r, 1);
            if ((lane & 31) == 0 && mv) {
                const float qn = qo[it] + r;
                q_edge[hrow + m] = qn;
                const float sg = sigf(qn);
                peB[hrow + m] = sg;
                peTB[vb + (size_t)m*SDIM + h] = sg;
            }
        }
    } else {
        const int i = row;
        if (i < 1 || i >= len) return;
        const int j0 = (blockIdx.y - 4) * 32;
        if (j0 >= len) return;
        const size_t irow = vb + (size_t)i*SDIM;
        const float4 peTi4 = *(const float4*)(peTA + irow + sqa);
        int jr[4];
        float4 hb[4], he[4], ptj[4];
        float qs[4], pq[4], s0[4], s1[4];
        #pragma unroll
        for (int it = 0; it < 4; ++it) {
            const int j = j0 + 8*it + 2*wave + half;
            jr[it] = j;
            const int jc = min(j, lm1);    // clamped row (address only)
            hb[it]  = *(const float4*)(s_hb + (size_t)b*S3 + (size_t)i*S2 + (size_t)jc*SDIM + sqa);
            he[it]  = *(const float4*)(s_he + (size_t)b*S3 + (size_t)jc*S2 + (size_t)i*SDIM + sqa);
            ptj[it] = *(const float4*)(peTA + vb + (size_t)jc*SDIM + sqa);
            qs[it]  = q_span[irow + jc];
            pq[it]  = psA[irow + jc];
            s0[it]  = split0[irow + jc];
            s1[it]  = split1[irow + jc];
        }
        __builtin_amdgcn_sched_barrier(0);
        #pragma unroll
        for (int it = 0; it < 4; ++it) {
            const int j = jr[it];
            const bool act = (j > i) && (j < len);
            float r = 0.f;
            #define TERM(C, F) { const int s = sq + C;                               \
                const float f = (act && s >= 1 && s < len && (s < i || s > j))       \
                                ? 1.f : 0.f;                                         \
                r += f * (hb[it].F*peTi4.F + he[it].F*ptj[it].F); }
            TERM(0, x) TERM(1, y) TERM(2, z) TERM(3, w)
            #undef TERM
            r += __shfl_xor(r, 16); r += __shfl_xor(r, 8); r += __shfl_xor(r, 4);
            r += __shfl_xor(r, 2);  r += __shfl_xor(r, 1);
            if ((lane & 31) == 0 && j >= 1 && j < len) {
                const float qn = qs[it] + r + pq[it] * (s0[it] + s1[it]);
                q_span[irow + j] = qn;
                psB[irow + j] = sigf(qn);
            }
        }
    }
}

extern "C" void kernel_launch(void* const* d_in, const int* in_sizes, int n_in,
                              void* d_out, int out_size, void* d_ws, size_t ws_size,
                              hipStream_t stream) {
    const float* s_edge  = (const float*)d_in[0];
    const float* s_const = (const float*)d_in[1];
    const float* s_sib   = (const float*)d_in[2];
    const float* s_cop   = (const float*)d_in[3];
    const float* s_grd   = (const float*)d_in[4];
    const float* s_ep    = (const float*)d_in[5];
    const float* s_split = (const float*)d_in[6];
    const float* s_hb    = (const float*)d_in[7];
    const float* s_he    = (const float*)d_in[8];
    const void*  em      = d_in[9];
    (void)in_sizes; (void)n_in; (void)out_size; (void)ws_size;

    float* q_edge = (float*)d_out;
    float* q_span = q_edge + (size_t)BB * S2;

    char* ws = (char*)d_ws;
    const size_t SZ = (size_t)BB * S2 * sizeof(float);   // 256 KiB
    float* split0 = (float*)(ws);
    float* split1 = (float*)(ws + 1*SZ);
    float* peA    = (float*)(ws + 2*SZ);
    float* peTA   = (float*)(ws + 3*SZ);
    float* psA    = (float*)(ws + 4*SZ);
    float* peB    = (float*)(ws + 5*SZ);
    float* peTB   = (float*)(ws + 6*SZ);
    float* psB    = (float*)(ws + 7*SZ);

    const int NB = BB * SDIM;  // 512
    hipLaunchKernelGGL(k_prep, dim3(NB, 2), dim3(256), 0, stream,
                       s_edge, s_const, s_split, em, q_edge, q_span,
                       split0, split1, peA, peB, peTA, peTB, psA, psB);
    for (int it = 0; it < 3; ++it) {
        const int s = it & 1;
        const float* peR  = s ? peB  : peA;
        const float* peTR = s ? peTB : peTA;
        const float* psR  = s ? psB  : psA;
        float* peW  = s ? peA  : peB;
        float* peTW = s ? peTA : peTB;
        float* psW  = s ? psA  : psB;
        hipLaunchKernelGGL(k_upd, dim3(dim3(NB, 8)), dim3(256), 0, stream,
                           s_sib, s_cop, s_grd, s_ep, s_hb, s_he,
                           peR, peTR, psR, split0, split1, em,
                           q_edge, q_span, peW, peTW, psW);
    }
}

// Round 3
// 276.073 us; speedup vs baseline: 1.1239x; 1.0092x over previous
//
#include <hip/hip_runtime.h>
#include <stdint.h>

#define BB 4
#define SDIM 128
#define S2 (SDIM*SDIM)          // 16384
#define S3 ((size_t)SDIM*S2)    // 2097152

// Per-wave probe: detect bool storage width (1B vs 4B) from structure
// (valid is a prefix of >=64 trues; element S-1 is always false), then
// return len[b] = popcount of the valid prefix. All 64 lanes participate.
__device__ __forceinline__ int probe_len(const void* em, int b, int lane) {
    const unsigned char* p8 = (const unsigned char*)em;
    const int* p32 = (const int*)em;
    const int t0 = lane, t1 = lane + 64;
    const size_t i0 = (size_t)b*S2 + (size_t)t0*SDIM + t0;
    const size_t i1 = (size_t)b*S2 + (size_t)t1*SDIM + t1;
    const unsigned char a0 = p8[i0], a1 = p8[i1];
    const bool ok = (a0 != 0) && (t1 != SDIM-1 || a1 == 0);
    const unsigned long long mok = __ballot(ok);
    const bool use8 = (mok == ~0ull);   // wave-uniform
    int v0, v1;
    if (use8) { v0 = (a0 != 0); v1 = (a1 != 0); }
    else      { v0 = (p32[i0] != 0); v1 = (p32[i1] != 0); }
    return __popcll(__ballot(v0)) + __popcll(__ballot(v1));
}

__device__ __forceinline__ float sigf(float x) { return 1.f / (1.f + expf(-x)); }

// Keep-alive pin: forces the loads producing these values to be issued (and
// thus all in flight together) BEFORE this point. IR passes cannot sink a
// load past an asm that consumes its result; sched_barrier alone is IntrNoMem
// and gets circumvented at IR level (round-2 lesson: VGPR=60 proved collapse).
#define PIN1(a)          asm volatile("" :: "v"(a))
#define PIN4(a,b,c,d)    asm volatile("" :: "v"(a), "v"(b), "v"(c), "v"(d))

// Fused: q init + pe/peT/ps init (both ping-pong buffers) + splitsum partials.
// Grid (B*S, 2). blockIdx.y splits the j-reduction. All 8 row-loads issued
// straight-line and PINNED in flight, then reduced -> one latency wait.
__global__ __launch_bounds__(256) void k_prep(
    const float* __restrict__ s_edge, const float* __restrict__ s_const,
    const float* __restrict__ s_split, const void* __restrict__ em,
    float* __restrict__ q_edge, float* __restrict__ q_span,
    float* __restrict__ split0, float* __restrict__ split1,
    float* __restrict__ peA, float* __restrict__ peB,
    float* __restrict__ peTA, float* __restrict__ peTB,
    float* __restrict__ psA, float* __restrict__ psB) {
    const int b = blockIdx.x >> 7, i = blockIdx.x & 127;
    const int y = blockIdx.y;
    const int tid = threadIdx.x, lane = tid & 63;
    const int len = probe_len(em, b, lane);
    const int lm1 = len - 1;
    const size_t vb = (size_t)b*S2;
    if (y == 0 && tid < SDIM) {
        const size_t ro = vb + (size_t)i*SDIM + tid;
        const float qe = s_edge[ro];
        const float qs = (i <= tid) ? s_const[ro] : s_const[vb + (size_t)tid*SDIM + i];
        q_edge[ro] = qe;
        q_span[ro] = qs;
        const float se = sigf(qe), ss = sigf(qs);
        peA[ro] = se; peB[ro] = se;
        psA[ro] = ss; psB[ro] = ss;
        const size_t to = vb + (size_t)tid*SDIM + i;
        peTA[to] = se; peTB[to] = se;
    }
    const int g = tid >> 5;            // j-group 0..7
    const int kq = (tid & 31) * 4;     // k base
    float4 acc = make_float4(0.f, 0.f, 0.f, 0.f);
    if (i >= 1 && i < len && kq < len) {
        const float* base = s_split + (size_t)b*S3 + (size_t)i*S2;
        const int j0 = i + g + 8*y;    // then stride 16; 8 steps cover j-i < 128
        float4 v[8]; int jv[8];
        #pragma unroll
        for (int t = 0; t < 8; ++t) {
            const int j = j0 + 16*t;
            jv[t] = j;
            const int jc = min(j, lm1);
            v[t] = *(const float4*)(base + (size_t)jc*SDIM + kq);
        }
        #pragma unroll
        for (int t = 0; t < 8; ++t) PIN1(v[t].x);
        #pragma unroll
        for (int t = 0; t < 8; ++t) {
            const int j = jv[t];
            const bool jb = (j < len);
            acc.x += (jb && j != kq+0) ? v[t].x : 0.f;
            acc.y += (jb && j != kq+1) ? v[t].y : 0.f;
            acc.z += (jb && j != kq+2) ? v[t].z : 0.f;
            acc.w += (jb && j != kq+3) ? v[t].w : 0.f;
        }
    }
    __shared__ float red[8][SDIM];
    *(float4*)&red[g][kq] = acc;
    __syncthreads();
    if (tid < SDIM) {
        float s = 0.f;
        #pragma unroll
        for (int gg = 0; gg < 8; ++gg) s += red[gg][tid];
        float* out = y ? split1 : split0;
        out[vb + (size_t)i*SDIM + tid] = (tid >= 1 && tid < len) ? s : 0.f;
    }
}

// Fused per-iteration update, v4: round-2 structure + keep-alive PINs so all
// ~25 loads per wave are genuinely in flight together (verified by VGPR count
// jumping to ~130). Ping-pong sigmoid epilogue unchanged.
__global__ __launch_bounds__(256) void k_upd(
    const float* __restrict__ s_sib, const float* __restrict__ s_cop,
    const float* __restrict__ s_grd, const float* __restrict__ s_ep,
    const float* __restrict__ s_hb,  const float* __restrict__ s_he,
    const float* __restrict__ peA, const float* __restrict__ peTA,
    const float* __restrict__ psA,
    const float* __restrict__ split0, const float* __restrict__ split1,
    const void* __restrict__ em,
    float* __restrict__ q_edge, float* __restrict__ q_span,
    float* __restrict__ peB, float* __restrict__ peTB, float* __restrict__ psB) {
    const int b = blockIdx.x >> 7, row = blockIdx.x & 127;
    const int tid = threadIdx.x, wave = tid >> 6, lane = tid & 63;
    const int half = lane >> 5, sq = (lane & 31) * 4;
    const int len = probe_len(em, b, lane);
    const int lm1 = len - 1;
    const int sqa = min(sq, lm1 & ~3);     // clamped column base (address only)
    const size_t vb = (size_t)b*S2;

    if (blockIdx.y < 4) {
        const int h = row;
        if (h >= len) return;
        const int m0 = blockIdx.y * 32;
        if (m0 >= len) return;
        const size_t tb = (size_t)b*S3 + (size_t)h*S2;
        const size_t hrow = vb + (size_t)h*SDIM;
        const float4 pe4 = *(const float4*)(peA + hrow + sqa);
        int   mr[4];
        float4 sib[4], cop[4], grd[4], epv[4], pet[4], psv[4];
        float qo[4];
        #pragma unroll
        for (int it = 0; it < 4; ++it) {
            const int m = m0 + 8*it + 2*wave + half;
            mr[it] = m;
            const int mc = min(m, lm1);    // clamped row (address only)
            const size_t ro = tb + (size_t)mc*SDIM + sqa;
            sib[it] = *(const float4*)(s_sib + ro);
            cop[it] = *(const float4*)(s_cop + ro);
            grd[it] = *(const float4*)(s_grd + ro);
            epv[it] = *(const float4*)(s_ep  + ro);
            const size_t vo = vb + (size_t)mc*SDIM + sqa;
            pet[it] = *(const float4*)(peTA + vo);
            psv[it] = *(const float4*)(psA  + vo);
            qo[it]  = q_edge[hrow + mc];
        }
        #pragma unroll
        for (int it = 0; it < 4; ++it) {
            PIN4(sib[it].x, cop[it].x, grd[it].x, epv[it].x);
            PIN4(pet[it].x, psv[it].x, qo[it],    pe4.x);
        }
        #pragma unroll
        for (int it = 0; it < 4; ++it) {
            const int m = mr[it];
            const bool mv = (m < len);
            float r = 0.f;
            #define TERM(C, F) { const int s = sq + C;                               \
                const bool bs = mv && (s < len) && (m != s);                         \
                const float fem = (bs && (h != s)) ? 1.f : 0.f;                      \
                const float fnc = (bs && ((m >= h && s >= h) || (m <= h && s <= h))) \
                                  ? 1.f : 0.f;                                       \
                r += fem * (sib[it].F*pe4.F + cop[it].F*pet[it].F + grd[it].F*psv[it].F) \
                   + fnc * (epv[it].F*psv[it].F); }
            TERM(0, x) TERM(1, y) TERM(2, z) TERM(3, w)
            #undef TERM
            r += __shfl_xor(r, 16); r += __shfl_xor(r, 8); r += __shfl_xor(r, 4);
            r += __shfl_xor(r, 2);  r += __shfl_xor(r, 1);
            if ((lane & 31) == 0 && mv) {
                const float qn = qo[it] + r;
                q_edge[hrow + m] = qn;
                const float sg = sigf(qn);
                peB[hrow + m] = sg;
                peTB[vb + (size_t)m*SDIM + h] = sg;
            }
        }
    } else {
        const int i = row;
        if (i < 1 || i >= len) return;
        const int j0 = (blockIdx.y - 4) * 32;
        if (j0 >= len) return;
        const size_t irow = vb + (size_t)i*SDIM;
        const float4 peTi4 = *(const float4*)(peTA + irow + sqa);
        int jr[4];
        float4 hb[4], he[4], ptj[4];
        float qs[4], pq[4], s0[4], s1[4];
        #pragma unroll
        for (int it = 0; it < 4; ++it) {
            const int j = j0 + 8*it + 2*wave + half;
            jr[it] = j;
            const int jc = min(j, lm1);    // clamped row (address only)
            hb[it]  = *(const float4*)(s_hb + (size_t)b*S3 + (size_t)i*S2 + (size_t)jc*SDIM + sqa);
            he[it]  = *(const float4*)(s_he + (size_t)b*S3 + (size_t)jc*S2 + (size_t)i*SDIM + sqa);
            ptj[it] = *(const float4*)(peTA + vb + (size_t)jc*SDIM + sqa);
            qs[it]  = q_span[irow + jc];
            pq[it]  = psA[irow + jc];
            s0[it]  = split0[irow + jc];
            s1[it]  = split1[irow + jc];
        }
        #pragma unroll
        for (int it = 0; it < 4; ++it) {
            PIN4(hb[it].x, he[it].x, ptj[it].x, qs[it]);
            PIN4(pq[it],   s0[it],   s1[it],    peTi4.x);
        }
        #pragma unroll
        for (int it = 0; it < 4; ++it) {
            const int j = jr[it];
            const bool act = (j > i) && (j < len);
            float r = 0.f;
            #define TERM(C, F) { const int s = sq + C;                               \
                const float f = (act && s >= 1 && s < len && (s < i || s > j))       \
                                ? 1.f : 0.f;                                         \
                r += f * (hb[it].F*peTi4.F + he[it].F*ptj[it].F); }
            TERM(0, x) TERM(1, y) TERM(2, z) TERM(3, w)
            #undef TERM
            r += __shfl_xor(r, 16); r += __shfl_xor(r, 8); r += __shfl_xor(r, 4);
            r += __shfl_xor(r, 2);  r += __shfl_xor(r, 1);
            if ((lane & 31) == 0 && j >= 1 && j < len) {
                const float qn = qs[it] + r + pq[it] * (s0[it] + s1[it]);
                q_span[irow + j] = qn;
                psB[irow + j] = sigf(qn);
            }
        }
    }
}

extern "C" void kernel_launch(void* const* d_in, const int* in_sizes, int n_in,
                              void* d_out, int out_size, void* d_ws, size_t ws_size,
                              hipStream_t stream) {
    const float* s_edge  = (const float*)d_in[0];
    const float* s_const = (const float*)d_in[1];
    const float* s_sib   = (const float*)d_in[2];
    const float* s_cop   = (const float*)d_in[3];
    const float* s_grd   = (const float*)d_in[4];
    const float* s_ep    = (const float*)d_in[5];
    const float* s_split = (const float*)d_in[6];
    const float* s_hb    = (const float*)d_in[7];
    const float* s_he    = (const float*)d_in[8];
    const void*  em      = d_in[9];
    (void)in_sizes; (void)n_in; (void)out_size; (void)ws_size;

    float* q_edge = (float*)d_out;
    float* q_span = q_edge + (size_t)BB * S2;

    char* ws = (char*)d_ws;
    const size_t SZ = (size_t)BB * S2 * sizeof(float);   // 256 KiB
    float* split0 = (float*)(ws);
    float* split1 = (float*)(ws + 1*SZ);
    float* peA    = (float*)(ws + 2*SZ);
    float* peTA   = (float*)(ws + 3*SZ);
    float* psA    = (float*)(ws + 4*SZ);
    float* peB    = (float*)(ws + 5*SZ);
    float* peTB   = (float*)(ws + 6*SZ);
    float* psB    = (float*)(ws + 7*SZ);

    const int NB = BB * SDIM;  // 512
    hipLaunchKernelGGL(k_prep, dim3(NB, 2), dim3(256), 0, stream,
                       s_edge, s_const, s_split, em, q_edge, q_span,
                       split0, split1, peA, peB, peTA, peTB, psA, psB);
    for (int it = 0; it < 3; ++it) {
        const int s = it & 1;
        const float* peR  = s ? peB  : peA;
        const float* peTR = s ? peTB : peTA;
        const float* psR  = s ? psB  : psA;
        float* peW  = s ? peA  : peB;
        float* peTW = s ? peTA : peTB;
        float* psW  = s ? psA  : psB;
        hipLaunchKernelGGL(k_upd, dim3(dim3(NB, 8)), dim3(256), 0, stream,
                           s_sib, s_cop, s_grd, s_ep, s_hb, s_he,
                           peR, peTR, psR, split0, split1, em,
                           q_edge, q_span, peW, peTW, psW);
    }
}